// Round 8
// baseline (697.971 us; speedup 1.0000x reference)
//
#include <hip/hip_runtime.h>
#include <hip/hip_bf16.h>

typedef __hip_bfloat16 bf16;
typedef unsigned short u16;

__device__ __forceinline__ float bf2f(bf16 v) { return __bfloat162float(v); }
__device__ __forceinline__ float us2f(u16 u) {
    union { unsigned int i; float f; } c; c.i = ((unsigned int)u) << 16; return c.f;
}

template<typename T> struct ST;
template<> struct ST<float> {
    using lds_t = float;
    static __device__ float ld(const float* p, int i) { return p[i]; }
    static __device__ void st(float* p, int i, float v) { p[i] = v; }
    static __device__ float lraw(const float* p, int i) { return p[i]; }
    static __device__ float l2f(float v) { return v; }
};
template<> struct ST<bf16> {
    using lds_t = u16;
    static __device__ float ld(const bf16* p, int i) { return bf2f(p[i]); }
    static __device__ void st(bf16* p, int i, float v) { p[i] = __float2bfloat16(v); }
    static __device__ u16 lraw(const bf16* p, int i) { return ((const u16*)p)[i]; }
    static __device__ float l2f(u16 v) { return us2f(v); }
};

// ---------------------------------------------------------------------------
// K1: km/qm/xm = conv1x1(x,{wk,wq,wx}) (+bias, km*=vessel). Inputs f32.
// ---------------------------------------------------------------------------
template<typename T>
__global__ __launch_bounds__(256) void k_proj(
    const float* __restrict__ x, const float* __restrict__ vessel,
    const float* __restrict__ wk, const float* __restrict__ bk,
    const float* __restrict__ wq, const float* __restrict__ bq,
    const float* __restrict__ wx, const float* __restrict__ bx,
    T* __restrict__ km, T* __restrict__ qm, bf16* __restrict__ xm,
    float* __restrict__ flag)
{
    __shared__ float xs[64 * 68];
    __shared__ float wch[96 * 64];
    const int tid = threadIdx.x;
    const int og = tid >> 6, px = tid & 63;
    const int b = blockIdx.x >> 6;
    const int p0 = (blockIdx.x & 63) * 64;
    if (blockIdx.x == 0 && tid == 0) flag[0] = 1.f;

    float acc[24];
#pragma unroll
    for (int j = 0; j < 24; ++j) {
        const int o = og * 24 + j;
        const float* bs = (o < 32) ? bk : ((o < 64) ? bq : bx);
        acc[j] = bs[o & 31];
    }
    for (int c0 = 0; c0 < 256; c0 += 64) {
        __syncthreads();
#pragma unroll
        for (int i = 0; i < 24; ++i) {
            const int idx = tid + i * 256;
            const int o = idx >> 6, cc = idx & 63;
            const float* wp = (o < 32) ? wk : ((o < 64) ? wq : wx);
            wch[o * 64 + cc] = wp[(o & 31) * 256 + c0 + cc];
        }
#pragma unroll
        for (int i = 0; i < 16; ++i) {
            const int idx = tid + i * 256;
            const int cc = idx >> 6, pl = idx & 63;
            xs[pl * 68 + cc] = x[(b * 256 + c0 + cc) * 4096 + p0 + pl];
        }
        __syncthreads();
#pragma unroll
        for (int c4 = 0; c4 < 16; ++c4) {
            const float4 xv = *(const float4*)&xs[px * 68 + c4 * 4];
#pragma unroll
            for (int j = 0; j < 24; ++j) {
                const float4 wv = *(const float4*)&wch[(og * 24 + j) * 64 + c4 * 4];
                acc[j] += wv.x * xv.x + wv.y * xv.y + wv.z * xv.z + wv.w * xv.w;
            }
        }
    }
    const float v = vessel[b * 4096 + p0 + px];
    const int gp = (b * 4096 + p0 + px) * 32;
#pragma unroll
    for (int j = 0; j < 24; ++j) {
        const int o = og * 24 + j;
        const int ch = o & 31;
        if (o < 32)      ST<T>::st(km, gp + ch, acc[j] * v);
        else if (o < 64) ST<T>::st(qm, gp + ch, acc[j]);
        else             xm[gp + ch] = __float2bfloat16(acc[j]);
    }
}

// ---------------------------------------------------------------------------
// K2: 4-scale local attention (nested-window fusion). OOB halo = 0 => s=0,
// matching reference zero-padded patches that sit in the softmax denom.
// ---------------------------------------------------------------------------
template<typename T>
__global__ __launch_bounds__(256) void k_attn(
    const T* __restrict__ km, const T* __restrict__ qm,
    const bf16* __restrict__ xm, T* __restrict__ pre,
    float* __restrict__ flag)
{
    __shared__ typename ST<T>::lds_t kT[256 * 33];
    __shared__ u16 xT[256 * 33];
    const int tid = threadIdx.x;
    const int b = blockIdx.x >> 6;
    const int tile = blockIdx.x & 63;
    const int h0 = (tile >> 3) * 8, w0 = (tile & 7) * 8;
    const u16* ux = (const u16*)xm;
    if (blockIdx.x == 0 && tid == 0) flag[0] = 1.f;

#pragma unroll
    for (int i = 0; i < 32; ++i) {
        const int idx = tid + i * 256;
        const int pos = idx >> 5, c = idx & 31;
        const int gh = h0 - 4 + (pos >> 4), gw = w0 - 4 + (pos & 15);
        typename ST<T>::lds_t kv = (typename ST<T>::lds_t)0;
        u16 xv = 0;
        if (gh >= 0 && gh < 64 && gw >= 0 && gw < 64) {
            const int g = ((b << 12) + (gh << 6) + gw) * 32 + c;
            kv = ST<T>::lraw(km, g); xv = ux[g];
        }
        kT[pos * 33 + c] = kv;
        xT[pos * 33 + c] = xv;
    }
    const int px = tid >> 2, cg = tid & 3;
    const int py = px >> 3, pxx = px & 7;
    const int gp = ((b << 12) + ((h0 + py) << 6) + (w0 + pxx)) * 32;
    float q[8];
#pragma unroll
    for (int i = 0; i < 8; ++i) q[i] = ST<T>::ld(qm, gp + cg * 8 + i);
    __syncthreads();

    float Z3 = 0.f, Z5 = 0.f, Z7 = 0.f, Z9 = 0.f;
    for (int j = 0; j < 81; ++j) {
        const int jd = j / 9;
        const int dy = jd - 4, dx = j - jd * 9 - 4;
        const int pos = (py + 4 + dy) * 16 + (pxx + 4 + dx);
        float s = 0.f;
#pragma unroll
        for (int i = 0; i < 8; ++i) s += ST<T>::l2f(kT[pos * 33 + cg * 8 + i]) * q[i];
        s += __shfl_xor(s, 1);
        s += __shfl_xor(s, 2);
        const float e = __expf(s);
        const int ady = dy < 0 ? -dy : dy, adx = dx < 0 ? -dx : dx;
        const int r = ady > adx ? ady : adx;
        if (r <= 1) Z3 += e;
        if (r <= 2) Z5 += e;
        if (r <= 3) Z7 += e;
        Z9 += e;
    }
    const float iZ3 = 1.f / Z3, iZ5 = 1.f / Z5, iZ7 = 1.f / Z7, iZ9 = 1.f / Z9;

    float acc[8];
#pragma unroll
    for (int i = 0; i < 8; ++i) acc[i] = 0.f;
    for (int j = 0; j < 81; ++j) {
        const int jd = j / 9;
        const int dy = jd - 4, dx = j - jd * 9 - 4;
        const int pos = (py + 4 + dy) * 16 + (pxx + 4 + dx);
        float s = 0.f;
#pragma unroll
        for (int i = 0; i < 8; ++i) s += ST<T>::l2f(kT[pos * 33 + cg * 8 + i]) * q[i];
        s += __shfl_xor(s, 1);
        s += __shfl_xor(s, 2);
        const float e = __expf(s);
        const int ady = dy < 0 ? -dy : dy, adx = dx < 0 ? -dx : dx;
        const int r = ady > adx ? ady : adx;
        float coef = iZ9;
        if (r <= 1) coef += iZ3;
        if (r <= 2) coef += iZ5;
        if (r <= 3) coef += iZ7;
        const float w = e * coef;
#pragma unroll
        for (int i = 0; i < 8; ++i) acc[i] += w * us2f(xT[pos * 33 + cg * 8 + i]);
    }
#pragma unroll
    for (int i = 0; i < 8; ++i) ST<T>::st(pre, gp + cg * 8 + i, acc[i]);
}

// ---------------------------------------------------------------------------
// K2b: partial S2 = pre^T pre + S1 = sum(pre), 256 px/blk
// ---------------------------------------------------------------------------
template<typename T>
__global__ __launch_bounds__(256) void k_cov(
    const T* __restrict__ pre, float* __restrict__ partials,
    float* __restrict__ flag)
{
    __shared__ float t[256 * 32];
    const int tid = threadIdx.x;
    const int p0 = blockIdx.x * 256;
    if (blockIdx.x == 0 && tid == 0) flag[0] = 1.f;
    for (int i = 0; i < 32; ++i) {
        const int idx = tid + i * 256;
        t[idx] = ST<T>::ld(pre, p0 * 32 + idx);
    }
    __syncthreads();
    const int i0 = tid >> 3, j0 = (tid & 7) * 4;
    float4 a = {0.f, 0.f, 0.f, 0.f};
    for (int p = 0; p < 256; ++p) {
        const float vi = t[p * 32 + i0];
        const float4 vj = *(const float4*)&t[p * 32 + j0];
        a.x += vi * vj.x; a.y += vi * vj.y; a.z += vi * vj.z; a.w += vi * vj.w;
    }
    *(float4*)&partials[blockIdx.x * 1056 + i0 * 32 + j0] = a;
    if (tid < 32) {
        float s = 0.f;
        for (int p = 0; p < 256; ++p) s += t[p * 32 + tid];
        partials[blockIdx.x * 1056 + 1024 + tid] = s;
    }
}

// ---------------------------------------------------------------------------
// K2c: BN constants. meanY[o]=wf_o.mu+bf[o]; var=wf_o S2 wf_o^T/N-(wf_o.mu)^2
// A = gamma*rsqrt(var+eps); S = beta - A*meanY (k_out adds bf into y).
// ---------------------------------------------------------------------------
__global__ __launch_bounds__(256) void k_stats(
    const float* __restrict__ partials, const float* __restrict__ wf,
    const float* __restrict__ bfb, const float* __restrict__ gamma,
    const float* __restrict__ beta,
    float* __restrict__ Aout, float* __restrict__ Sout,
    float* __restrict__ flag)
{
    __shared__ float cov[1024];
    __shared__ float mu[32];
    const int tid = threadIdx.x;
    if (tid == 0) flag[0] = 1.f;
    float4 a = {0.f, 0.f, 0.f, 0.f};
    for (int blk = 0; blk < 64; ++blk) {
        const float4 p = *(const float4*)&partials[blk * 1056 + tid * 4];
        a.x += p.x; a.y += p.y; a.z += p.z; a.w += p.w;
    }
    *(float4*)&cov[tid * 4] = a;
    if (tid < 32) {
        float s = 0.f;
        for (int blk = 0; blk < 64; ++blk) s += partials[blk * 1056 + 1024 + tid];
        mu[tid] = s * (1.f / 16384.f);
    }
    __syncthreads();
    float wo[32];
#pragma unroll
    for (int c = 0; c < 32; ++c) wo[c] = wf[tid * 32 + c];
    float mv = 0.f;
#pragma unroll
    for (int c = 0; c < 32; ++c) mv += wo[c] * mu[c];
    float qacc = 0.f;
    for (int i2 = 0; i2 < 32; ++i2) {
        float t = 0.f;
#pragma unroll
        for (int j2 = 0; j2 < 32; ++j2) t += wo[j2] * cov[i2 * 32 + j2];
        qacc += wo[i2] * t;
    }
    const float var = qacc * (1.f / 16384.f) - mv * mv;
    const float A = gamma[tid] * rsqrtf(var + 1e-5f);
    Aout[tid] = A;
    Sout[tid] = beta[tid] - A * (mv + bfb[tid]);
}

// ---------------------------------------------------------------------------
// K3: out = x + A*(wf.pre + bf) + S -- OUTPUT IS FLOAT32.
// ---------------------------------------------------------------------------
template<typename T>
__global__ __launch_bounds__(256) void k_out(
    const T* __restrict__ pre, const float* __restrict__ wf,
    const float* __restrict__ bfb, const float* __restrict__ x,
    const float* __restrict__ A, const float* __restrict__ S,
    float* __restrict__ out, const float* __restrict__ flags, int code_extra)
{
    __shared__ float wfL[256 * 32];
    __shared__ float pL[64 * 33];
    const int tid = threadIdx.x;
    const int gp0 = blockIdx.x * 64;
    const int b = gp0 >> 12, p0 = gp0 & 4095;
    for (int i = 0; i < 32; ++i) {
        const int idx = tid + i * 256;
        wfL[idx] = wf[idx];
    }
    for (int i = 0; i < 8; ++i) {
        const int idx = tid + i * 256;
        const int p = idx >> 5, c = idx & 31;
        pL[p * 33 + c] = ST<T>::ld(pre, gp0 * 32 + idx);
    }
    __syncthreads();
    const int og = tid >> 6, px = tid & 63;
    for (int jj = 0; jj < 64; ++jj) {
        const int o = og * 64 + jj;
        float acc = bfb[o];
#pragma unroll
        for (int c = 0; c < 32; ++c) acc += wfL[o * 32 + c] * pL[px * 33 + c];
        const int ga = ((b << 8) + o) * 4096 + p0 + px;
        out[ga] = x[ga] + A[o] * acc + S[o];
    }
    if (blockIdx.x == 0 && tid == 0) {
        int code = code_extra;
        if (flags[0] != 1.f) code += 1024;
        if (flags[1] != 1.f) code += 2048;
        if (flags[2] != 1.f) code += 4096;
        if (flags[3] != 1.f) code += 8192;
        if (code != 0) out[0] = 16384.f + (float)code;
    }
}

// ---------------------------------------------------------------------------
// K4: diagnostic. Phase 0: interior pixel (b1,20,30); phase 1: corner
// (b0,0,0) with zero padding. On mismatch out[0] = 4096 + 32*code.
// bits: 1 km, 2 qm, 4 xm, 8 pre!=brute, 16 pre!=softmax(pipeline maps),
// 32 A insane, 64 S insane, 128 corner pre!=brute.
// ---------------------------------------------------------------------------
template<typename T>
__global__ __launch_bounds__(256) void k_diag(
    const float* __restrict__ x, const float* __restrict__ vessel,
    const float* __restrict__ wk, const float* __restrict__ bk,
    const float* __restrict__ wq, const float* __restrict__ bq,
    const float* __restrict__ wx, const float* __restrict__ bx,
    const T* __restrict__ km, const T* __restrict__ qm,
    const bf16* __restrict__ xm, const T* __restrict__ pre,
    const float* __restrict__ A, const float* __restrict__ S,
    float* __restrict__ out)
{
    __shared__ float kR[81 * 32];
    __shared__ float xR[81 * 32];
    __shared__ float qR[32];
    __shared__ float sbuf[81];
    const int tid = threadIdx.x;
    int code = 0;

    for (int phase = 0; phase < 2; ++phase) {
        const int B0 = phase ? 0 : 1, H0 = phase ? 0 : 20, W0 = phase ? 0 : 30;
        for (int t = tid; t < 81 * 32 * 2 + 32; t += 256) {
            int kind, n, c;
            if (t < 81 * 32)          { kind = 0; n = t / 32;             c = t % 32; }
            else if (t < 2 * 81 * 32) { kind = 1; n = (t - 81 * 32) / 32; c = (t - 81 * 32) % 32; }
            else                      { kind = 2; n = 40;                 c = t - 2 * 81 * 32; }
            const int dy = n / 9 - 4, dx = n % 9 - 4;
            const int gh = H0 + dy, gw = W0 + dx;
            float r = 0.f;
            if (gh >= 0 && gh < 64 && gw >= 0 && gw < 64) {
                const int gpix = gh * 64 + gw;
                const float* w  = (kind == 0) ? wk : ((kind == 1) ? wx : wq);
                const float* bb = (kind == 0) ? bk : ((kind == 1) ? bx : bq);
                float acc = bb[c];
                for (int cc = 0; cc < 256; ++cc)
                    acc += x[(B0 * 256 + cc) * 4096 + gpix] * w[c * 256 + cc];
                r = (kind == 0) ? acc * vessel[B0 * 4096 + gpix] : acc;
            }
            if (kind == 0)      kR[n * 32 + c] = r;
            else if (kind == 1) xR[n * 32 + c] = r;
            else                qR[c] = r;
        }
        __syncthreads();
        for (int n = tid; n < 81; n += 256) {
            float s = 0.f;
            for (int c = 0; c < 32; ++c) s += kR[n * 32 + c] * qR[c];
            sbuf[n] = s;
        }
        __syncthreads();
        if (tid == 0) {
            const int gp = (B0 * 4096 + H0 * 64 + W0) * 32;
            if (phase == 0) {
                for (int c = 0; c < 32; ++c) {
                    const float rk = kR[40 * 32 + c], rq = qR[c], rx = xR[40 * 32 + c];
                    if (fabsf(ST<T>::ld(km, gp + c) - rk) > 0.08f * fmaxf(1.f, fabsf(rk))) code |= 1;
                    if (fabsf(ST<T>::ld(qm, gp + c) - rq) > 0.08f * fmaxf(1.f, fabsf(rq))) code |= 2;
                    if (fabsf(bf2f(xm[gp + c]) - rx) > 0.08f * fmaxf(1.f, fabsf(rx))) code |= 4;
                }
            }
            // brute pre from reference semantics (4 literal softmaxes)
            float preR[32];
            for (int c = 0; c < 32; ++c) preR[c] = 0.f;
            for (int rad = 1; rad <= 4; ++rad) {
                float Z = 0.f;
                for (int n = 0; n < 81; ++n) {
                    const int dy = n / 9 - 4, dx = n % 9 - 4;
                    if (dy >= -rad && dy <= rad && dx >= -rad && dx <= rad)
                        Z += __expf(sbuf[n]);
                }
                for (int n = 0; n < 81; ++n) {
                    const int dy = n / 9 - 4, dx = n % 9 - 4;
                    if (dy >= -rad && dy <= rad && dx >= -rad && dx <= rad) {
                        const float wgt = __expf(sbuf[n]) / Z;
                        for (int c = 0; c < 32; ++c) preR[c] += wgt * xR[n * 32 + c];
                    }
                }
            }
            const int bit = phase ? 128 : 8;
            for (int c = 0; c < 32; ++c) {
                const float pp = ST<T>::ld(pre, gp + c);
                if (fabsf(pp - preR[c]) > 0.10f * fmaxf(1.f, fabsf(preR[c]))) { code |= bit; break; }
            }
            if (phase == 0) {
                if (!(A[7] > 0.005f && A[7] < 200.f)) code |= 32;
                if (!(fabsf(S[7]) < 200.f)) code |= 64;
            }
        }
        __syncthreads();
    }
    if (tid == 0 && code != 0) out[0] = 4096.f + 32.f * (float)code;
}

__global__ void k_sent(float* out, float code)
{
    if (blockIdx.x == 0 && threadIdx.x == 0) out[0] = code;
}

// ---------------------------------------------------------------------------
template<typename T>
static void run_pipeline(const float* x, const float* vessel,
                         const float* wk, const float* bk,
                         const float* wq, const float* bq,
                         const float* wx, const float* bx,
                         const float* wf, const float* bfb,
                         const float* gamma, const float* beta,
                         float* out, char* ws,
                         size_t o_km, size_t o_qm, size_t o_xm, size_t o_pre,
                         size_t o_part, size_t o_A, size_t o_S, size_t o_flags,
                         int code_extra, hipStream_t stream)
{
    T* km = (T*)(ws + o_km);
    T* qm = (T*)(ws + o_qm);
    bf16* xm = (bf16*)(ws + o_xm);
    T* pre = (T*)(ws + o_pre);
    float* partials = (float*)(ws + o_part);
    float* Abuf = (float*)(ws + o_A);
    float* Sbuf = (float*)(ws + o_S);
    float* flags = (float*)(ws + o_flags);

    k_proj<T><<<256, 256, 0, stream>>>(x, vessel, wk, bk, wq, bq, wx, bx,
                                       km, qm, xm, flags + 0);
    k_attn<T><<<256, 256, 0, stream>>>(km, qm, xm, pre, flags + 1);
    k_cov<T><<<64, 256, 0, stream>>>(pre, partials, flags + 2);
    k_stats<<<1, 256, 0, stream>>>(partials, wf, bfb, gamma, beta,
                                   Abuf, Sbuf, flags + 3);
    k_out<T><<<256, 256, 0, stream>>>(pre, wf, bfb, x, Abuf, Sbuf, out,
                                      flags, code_extra);
    k_diag<T><<<1, 256, 0, stream>>>(x, vessel, wk, bk, wq, bq, wx, bx,
                                     km, qm, xm, pre, Abuf, Sbuf, out);
}

extern "C" void kernel_launch(void* const* d_in, const int* in_sizes, int n_in,
                              void* d_out, int out_size, void* d_ws, size_t ws_size,
                              hipStream_t stream)
{
    (void)out_size;
    float* out = (float*)d_out;
    char* ws = (char*)d_ws;

    static const long long SZ[12] = {4194304, 16384, 8192, 32, 8192, 32,
                                     8192, 32, 8192, 256, 256, 256};
    static const int AMAP[12] = {11, 6, 8, 2, 9, 3, 10, 4, 7, 1, 5, 0};

    int map[12];
    for (int i = 0; i < 12; ++i) map[i] = i;
    int code_extra = 0;
    bool ok = false;
    if (n_in == 12 && in_sizes) {
        bool id_e = true, id_b = true, al_e = true, al_b = true;
        long long alp[12];
        for (int j = 0; j < 12; ++j) alp[AMAP[j]] = SZ[j];
        for (int i = 0; i < 12; ++i) {
            const long long s = in_sizes[i];
            if (s != SZ[i]) id_e = false;
            if (s != SZ[i] * 4) id_b = false;
            if (s != alp[i]) al_e = false;
            if (s != alp[i] * 4) al_b = false;
        }
        if (id_e || id_b) ok = true;
        else if (al_e || al_b) {
            for (int j = 0; j < 12; ++j) map[j] = AMAP[j];
            ok = true;
        }
    }
    if (!ok) code_extra += 256;

    const float* x      = (const float*)d_in[map[0]];
    const float* vessel = (const float*)d_in[map[1]];
    const float* wk     = (const float*)d_in[map[2]];
    const float* bk     = (const float*)d_in[map[3]];
    const float* wq     = (const float*)d_in[map[4]];
    const float* bq     = (const float*)d_in[map[5]];
    const float* wx     = (const float*)d_in[map[6]];
    const float* bx     = (const float*)d_in[map[7]];
    const float* wf     = (const float*)d_in[map[8]];
    const float* bfb    = (const float*)d_in[map[9]];
    const float* gamma  = (const float*)d_in[map[10]];
    const float* beta   = (const float*)d_in[map[11]];

    const size_t NEED_BIG = 7612432, NEED_SMALL = 4466704;
    if (ws_size >= NEED_BIG) {
        run_pipeline<float>(x, vessel, wk, bk, wq, bq, wx, bx, wf, bfb, gamma,
                            beta, out, ws,
                            0, 2097152, 4194304, 5242880,
                            7340032, 7610368, 7611392, 7612416,
                            code_extra, stream);
    } else if (ws_size >= NEED_SMALL) {
        run_pipeline<bf16>(x, vessel, wk, bk, wq, bq, wx, bx, wf, bfb, gamma,
                           beta, out, ws,
                           0, 1048576, 2097152, 3145728,
                           4194304, 4464640, 4465664, 4466688,
                           code_extra, stream);
    } else {
        k_sent<<<1, 64, 0, stream>>>(out, 16384.f + 512.f + (float)code_extra);
    }
}

// Round 9
// 240.489 us; speedup vs baseline: 2.9023x; 2.9023x over previous
//
#include <hip/hip_runtime.h>
#include <hip/hip_bf16.h>

typedef __hip_bfloat16 bf16;
typedef unsigned short u16;

__device__ __forceinline__ float bf2f(bf16 v) { return __bfloat162float(v); }
__device__ __forceinline__ float us2f(u16 u) {
    union { unsigned int i; float f; } c; c.i = ((unsigned int)u) << 16; return c.f;
}

template<typename T> struct ST;
template<> struct ST<float> {
    using lds_t = float;
    static __device__ float ld(const float* p, int i) { return p[i]; }
    static __device__ void st(float* p, int i, float v) { p[i] = v; }
    static __device__ float lraw(const float* p, int i) { return p[i]; }
    static __device__ float l2f(float v) { return v; }
};
template<> struct ST<bf16> {
    using lds_t = u16;
    static __device__ float ld(const bf16* p, int i) { return bf2f(p[i]); }
    static __device__ void st(bf16* p, int i, float v) { p[i] = __float2bfloat16(v); }
    static __device__ u16 lraw(const bf16* p, int i) { return ((const u16*)p)[i]; }
    static __device__ float l2f(u16 v) { return us2f(v); }
};

// ---------------------------------------------------------------------------
// K1: km/qm/xm = conv1x1(x,{wk,wq,wx}) (+bias, km*=vessel). Inputs f32.
// (unchanged from the round-8 PASS)
// ---------------------------------------------------------------------------
template<typename T>
__global__ __launch_bounds__(256) void k_proj(
    const float* __restrict__ x, const float* __restrict__ vessel,
    const float* __restrict__ wk, const float* __restrict__ bk,
    const float* __restrict__ wq, const float* __restrict__ bq,
    const float* __restrict__ wx, const float* __restrict__ bx,
    T* __restrict__ km, T* __restrict__ qm, bf16* __restrict__ xm)
{
    __shared__ float xs[64 * 68];
    __shared__ float wch[96 * 64];
    const int tid = threadIdx.x;
    const int og = tid >> 6, px = tid & 63;
    const int b = blockIdx.x >> 6;
    const int p0 = (blockIdx.x & 63) * 64;

    float acc[24];
#pragma unroll
    for (int j = 0; j < 24; ++j) {
        const int o = og * 24 + j;
        const float* bs = (o < 32) ? bk : ((o < 64) ? bq : bx);
        acc[j] = bs[o & 31];
    }
    for (int c0 = 0; c0 < 256; c0 += 64) {
        __syncthreads();
#pragma unroll
        for (int i = 0; i < 24; ++i) {
            const int idx = tid + i * 256;
            const int o = idx >> 6, cc = idx & 63;
            const float* wp = (o < 32) ? wk : ((o < 64) ? wq : wx);
            wch[o * 64 + cc] = wp[(o & 31) * 256 + c0 + cc];
        }
#pragma unroll
        for (int i = 0; i < 16; ++i) {
            const int idx = tid + i * 256;
            const int cc = idx >> 6, pl = idx & 63;
            xs[pl * 68 + cc] = x[(b * 256 + c0 + cc) * 4096 + p0 + pl];
        }
        __syncthreads();
#pragma unroll
        for (int c4 = 0; c4 < 16; ++c4) {
            const float4 xv = *(const float4*)&xs[px * 68 + c4 * 4];
#pragma unroll
            for (int j = 0; j < 24; ++j) {
                const float4 wv = *(const float4*)&wch[(og * 24 + j) * 64 + c4 * 4];
                acc[j] += wv.x * xv.x + wv.y * xv.y + wv.z * xv.z + wv.w * xv.w;
            }
        }
    }
    const float v = vessel[b * 4096 + p0 + px];
    const int gp = (b * 4096 + p0 + px) * 32;
#pragma unroll
    for (int j = 0; j < 24; ++j) {
        const int o = og * 24 + j;
        const int ch = o & 31;
        if (o < 32)      ST<T>::st(km, gp + ch, acc[j] * v);
        else if (o < 64) ST<T>::st(qm, gp + ch, acc[j]);
        else             xm[gp + ch] = __float2bfloat16(acc[j]);
    }
}

// ---------------------------------------------------------------------------
// K2: 4-scale local attention (nested-window fusion). OOB halo = 0 => s=0,
// matching reference zero-padded patches in the softmax denominator.
// (unchanged from the round-8 PASS)
// ---------------------------------------------------------------------------
template<typename T>
__global__ __launch_bounds__(256) void k_attn(
    const T* __restrict__ km, const T* __restrict__ qm,
    const bf16* __restrict__ xm, T* __restrict__ pre)
{
    __shared__ typename ST<T>::lds_t kT[256 * 33];
    __shared__ u16 xT[256 * 33];
    const int tid = threadIdx.x;
    const int b = blockIdx.x >> 6;
    const int tile = blockIdx.x & 63;
    const int h0 = (tile >> 3) * 8, w0 = (tile & 7) * 8;
    const u16* ux = (const u16*)xm;

#pragma unroll
    for (int i = 0; i < 32; ++i) {
        const int idx = tid + i * 256;
        const int pos = idx >> 5, c = idx & 31;
        const int gh = h0 - 4 + (pos >> 4), gw = w0 - 4 + (pos & 15);
        typename ST<T>::lds_t kv = (typename ST<T>::lds_t)0;
        u16 xv = 0;
        if (gh >= 0 && gh < 64 && gw >= 0 && gw < 64) {
            const int g = ((b << 12) + (gh << 6) + gw) * 32 + c;
            kv = ST<T>::lraw(km, g); xv = ux[g];
        }
        kT[pos * 33 + c] = kv;
        xT[pos * 33 + c] = xv;
    }
    const int px = tid >> 2, cg = tid & 3;
    const int py = px >> 3, pxx = px & 7;
    const int gp = ((b << 12) + ((h0 + py) << 6) + (w0 + pxx)) * 32;
    float q[8];
#pragma unroll
    for (int i = 0; i < 8; ++i) q[i] = ST<T>::ld(qm, gp + cg * 8 + i);
    __syncthreads();

    float Z3 = 0.f, Z5 = 0.f, Z7 = 0.f, Z9 = 0.f;
    for (int j = 0; j < 81; ++j) {
        const int jd = j / 9;
        const int dy = jd - 4, dx = j - jd * 9 - 4;
        const int pos = (py + 4 + dy) * 16 + (pxx + 4 + dx);
        float s = 0.f;
#pragma unroll
        for (int i = 0; i < 8; ++i) s += ST<T>::l2f(kT[pos * 33 + cg * 8 + i]) * q[i];
        s += __shfl_xor(s, 1);
        s += __shfl_xor(s, 2);
        const float e = __expf(s);
        const int ady = dy < 0 ? -dy : dy, adx = dx < 0 ? -dx : dx;
        const int r = ady > adx ? ady : adx;
        if (r <= 1) Z3 += e;
        if (r <= 2) Z5 += e;
        if (r <= 3) Z7 += e;
        Z9 += e;
    }
    const float iZ3 = 1.f / Z3, iZ5 = 1.f / Z5, iZ7 = 1.f / Z7, iZ9 = 1.f / Z9;

    float acc[8];
#pragma unroll
    for (int i = 0; i < 8; ++i) acc[i] = 0.f;
    for (int j = 0; j < 81; ++j) {
        const int jd = j / 9;
        const int dy = jd - 4, dx = j - jd * 9 - 4;
        const int pos = (py + 4 + dy) * 16 + (pxx + 4 + dx);
        float s = 0.f;
#pragma unroll
        for (int i = 0; i < 8; ++i) s += ST<T>::l2f(kT[pos * 33 + cg * 8 + i]) * q[i];
        s += __shfl_xor(s, 1);
        s += __shfl_xor(s, 2);
        const float e = __expf(s);
        const int ady = dy < 0 ? -dy : dy, adx = dx < 0 ? -dx : dx;
        const int r = ady > adx ? ady : adx;
        float coef = iZ9;
        if (r <= 1) coef += iZ3;
        if (r <= 2) coef += iZ5;
        if (r <= 3) coef += iZ7;
        const float w = e * coef;
#pragma unroll
        for (int i = 0; i < 8; ++i) acc[i] += w * us2f(xT[pos * 33 + cg * 8 + i]);
    }
#pragma unroll
    for (int i = 0; i < 8; ++i) ST<T>::st(pre, gp + cg * 8 + i, acc[i]);
}

// ---------------------------------------------------------------------------
// K2b: partial S2 = pre^T pre + S1 = sum(pre), 256 px/blk (unchanged)
// ---------------------------------------------------------------------------
template<typename T>
__global__ __launch_bounds__(256) void k_cov(
    const T* __restrict__ pre, float* __restrict__ partials)
{
    __shared__ float t[256 * 32];
    const int tid = threadIdx.x;
    const int p0 = blockIdx.x * 256;
    for (int i = 0; i < 32; ++i) {
        const int idx = tid + i * 256;
        t[idx] = ST<T>::ld(pre, p0 * 32 + idx);
    }
    __syncthreads();
    const int i0 = tid >> 3, j0 = (tid & 7) * 4;
    float4 a = {0.f, 0.f, 0.f, 0.f};
    for (int p = 0; p < 256; ++p) {
        const float vi = t[p * 32 + i0];
        const float4 vj = *(const float4*)&t[p * 32 + j0];
        a.x += vi * vj.x; a.y += vi * vj.y; a.z += vi * vj.z; a.w += vi * vj.w;
    }
    *(float4*)&partials[blockIdx.x * 1056 + i0 * 32 + j0] = a;
    if (tid < 32) {
        float s = 0.f;
        for (int p = 0; p < 256; ++p) s += t[p * 32 + tid];
        partials[blockIdx.x * 1056 + 1024 + tid] = s;
    }
}

// ---------------------------------------------------------------------------
// K2c: BN constants (unchanged)
// ---------------------------------------------------------------------------
__global__ __launch_bounds__(256) void k_stats(
    const float* __restrict__ partials, const float* __restrict__ wf,
    const float* __restrict__ bfb, const float* __restrict__ gamma,
    const float* __restrict__ beta,
    float* __restrict__ Aout, float* __restrict__ Sout)
{
    __shared__ float cov[1024];
    __shared__ float mu[32];
    const int tid = threadIdx.x;
    float4 a = {0.f, 0.f, 0.f, 0.f};
    for (int blk = 0; blk < 64; ++blk) {
        const float4 p = *(const float4*)&partials[blk * 1056 + tid * 4];
        a.x += p.x; a.y += p.y; a.z += p.z; a.w += p.w;
    }
    *(float4*)&cov[tid * 4] = a;
    if (tid < 32) {
        float s = 0.f;
        for (int blk = 0; blk < 64; ++blk) s += partials[blk * 1056 + 1024 + tid];
        mu[tid] = s * (1.f / 16384.f);
    }
    __syncthreads();
    float wo[32];
#pragma unroll
    for (int c = 0; c < 32; ++c) wo[c] = wf[tid * 32 + c];
    float mv = 0.f;
#pragma unroll
    for (int c = 0; c < 32; ++c) mv += wo[c] * mu[c];
    float qacc = 0.f;
    for (int i2 = 0; i2 < 32; ++i2) {
        float t = 0.f;
#pragma unroll
        for (int j2 = 0; j2 < 32; ++j2) t += wo[j2] * cov[i2 * 32 + j2];
        qacc += wo[i2] * t;
    }
    const float var = qacc * (1.f / 16384.f) - mv * mv;
    const float A = gamma[tid] * rsqrtf(var + 1e-5f);
    Aout[tid] = A;
    Sout[tid] = beta[tid] - A * (mv + bfb[tid]);
}

// ---------------------------------------------------------------------------
// K3: out = x + A*(wf.pre + bf) + S, f32 out. Register-blocked: pixel
// fragment held in 8 float4 registers; wf read as float4 (4x fewer LDS ops
// than the scalar round-8 version). 256 thr = 4 og x 64 px.
// ---------------------------------------------------------------------------
template<typename T>
__global__ __launch_bounds__(256) void k_out(
    const T* __restrict__ pre, const float* __restrict__ wf,
    const float* __restrict__ bfb, const float* __restrict__ x,
    const float* __restrict__ A, const float* __restrict__ S,
    float* __restrict__ out)
{
    __shared__ float wfL[256 * 32];  // 32768 B
    __shared__ float pL[64 * 36];    //  9216 B (pad 36 keeps float4 align)
    const int tid = threadIdx.x;
    const int gp0 = blockIdx.x * 64;
    const int b = gp0 >> 12, p0 = gp0 & 4095;
#pragma unroll
    for (int i = 0; i < 8; ++i) {
        const int idx4 = tid + i * 256;          // 2048 float4 groups
        *(float4*)&wfL[idx4 * 4] = *(const float4*)&wf[idx4 * 4];
    }
    for (int i = 0; i < 8; ++i) {
        const int idx = tid + i * 256;           // 0..2047
        const int p = idx >> 5, c = idx & 31;
        pL[p * 36 + c] = ST<T>::ld(pre, gp0 * 32 + idx);
    }
    __syncthreads();
    const int og = tid >> 6, px = tid & 63;
    float4 pv[8];
#pragma unroll
    for (int c4 = 0; c4 < 8; ++c4)
        pv[c4] = *(const float4*)&pL[px * 36 + c4 * 4];
#pragma unroll
    for (int g = 0; g < 4; ++g) {
        float acc[16];
#pragma unroll
        for (int jj = 0; jj < 16; ++jj) acc[jj] = bfb[og * 64 + g * 16 + jj];
#pragma unroll
        for (int c4 = 0; c4 < 8; ++c4) {
            const float4 xv = pv[c4];
#pragma unroll
            for (int jj = 0; jj < 16; ++jj) {
                const float4 wv = *(const float4*)&wfL[(og * 64 + g * 16 + jj) * 32 + c4 * 4];
                acc[jj] += wv.x * xv.x + wv.y * xv.y + wv.z * xv.z + wv.w * xv.w;
            }
        }
#pragma unroll
        for (int jj = 0; jj < 16; ++jj) {
            const int o = og * 64 + g * 16 + jj;
            const int ga = ((b << 8) + o) * 4096 + p0 + px;
            out[ga] = x[ga] + A[o] * acc[jj] + S[o];
        }
    }
}

// ---------------------------------------------------------------------------
template<typename T>
static void run_pipeline(const float* x, const float* vessel,
                         const float* wk, const float* bk,
                         const float* wq, const float* bq,
                         const float* wx, const float* bx,
                         const float* wf, const float* bfb,
                         const float* gamma, const float* beta,
                         float* out, char* ws,
                         size_t o_km, size_t o_qm, size_t o_xm, size_t o_pre,
                         size_t o_part, size_t o_A, size_t o_S,
                         hipStream_t stream)
{
    T* km = (T*)(ws + o_km);
    T* qm = (T*)(ws + o_qm);
    bf16* xm = (bf16*)(ws + o_xm);
    T* pre = (T*)(ws + o_pre);
    float* partials = (float*)(ws + o_part);
    float* Abuf = (float*)(ws + o_A);
    float* Sbuf = (float*)(ws + o_S);

    k_proj<T><<<256, 256, 0, stream>>>(x, vessel, wk, bk, wq, bq, wx, bx,
                                       km, qm, xm);
    k_attn<T><<<256, 256, 0, stream>>>(km, qm, xm, pre);
    k_cov<T><<<64, 256, 0, stream>>>(pre, partials);
    k_stats<<<1, 256, 0, stream>>>(partials, wf, bfb, gamma, beta, Abuf, Sbuf);
    k_out<T><<<256, 256, 0, stream>>>(pre, wf, bfb, x, Abuf, Sbuf, out);
}

extern "C" void kernel_launch(void* const* d_in, const int* in_sizes, int n_in,
                              void* d_out, int out_size, void* d_ws, size_t ws_size,
                              hipStream_t stream)
{
    (void)in_sizes; (void)n_in; (void)out_size;
    float* out = (float*)d_out;
    char* ws = (char*)d_ws;

    const float* x      = (const float*)d_in[0];
    const float* vessel = (const float*)d_in[1];
    const float* wk     = (const float*)d_in[2];
    const float* bk     = (const float*)d_in[3];
    const float* wq     = (const float*)d_in[4];
    const float* bq     = (const float*)d_in[5];
    const float* wx     = (const float*)d_in[6];
    const float* bx     = (const float*)d_in[7];
    const float* wf     = (const float*)d_in[8];
    const float* bfb    = (const float*)d_in[9];
    const float* gamma  = (const float*)d_in[10];
    const float* beta   = (const float*)d_in[11];

    const size_t NEED_BIG = 7612432, NEED_SMALL = 4466704;
    if (ws_size >= NEED_BIG) {
        run_pipeline<float>(x, vessel, wk, bk, wq, bq, wx, bx, wf, bfb, gamma,
                            beta, out, ws,
                            0, 2097152, 4194304, 5242880,
                            7340032, 7610368, 7611392, stream);
    } else if (ws_size >= NEED_SMALL) {
        run_pipeline<bf16>(x, vessel, wk, bk, wq, bq, wx, bx, wf, bfb, gamma,
                           beta, out, ws,
                           0, 1048576, 2097152, 3145728,
                           4194304, 4464640, 4465664, stream);
    }
}